// Round 10
// baseline (299.325 us; speedup 1.0000x reference)
//
#include <hip/hip_runtime.h>
#include <hip/hip_bf16.h>
#include <stdint.h>

// VQ: x [N=131072, D=64] fp32, E [D=64, K=1024] fp32.
// R15: ENTIRE fp16 B table (128 KB) staged into LDS once; the 64-tile loop
// has ZERO global memory traffic. R9-R14 invariant: per-tile global B loads
// leave an uncoverable L2 chain at 1-4 waves/SIMD (90-245us). gfx950 allows
// 160KB LDS/WG (8-phase template uses 128KB): one 512-thread block per CU
// (grid 256, 512 rows/block, 4 rowsets/wave), stage table via 16x
// global_load_lds(16B)/thread, one __syncthreads, then per tile just
// 2x ds_read_b128 + esq read + 8 MFMA + min-update (ds ~120cyc covered by
// depth-1 register prefetch against ~240cyc body). Staging ~1-2us once.
// fp16 1-term screen + TAU=0.01 + wave-parallel fp64 refine: validated
// end-to-end in R13/R14 (absmax=0 both).
// Verified facts used: A[m=lane&15][k=(lane>>4)*8+j] (m89/m91/m120, f16/bf16
// family), C/D col=lane&15 row=(lane>>4)*4+reg (m89/m91, dtype-independent
// m121-m128), frag types 8xhalf / float4; global_load_lds wave-uniform dst
// + lane*16 (m104/m108).

typedef unsigned long long u64;
typedef _Float16 half8 __attribute__((ext_vector_type(8)));
typedef float f32x4 __attribute__((ext_vector_type(4)));

constexpr int D = 64;
constexpr int K = 1024;
constexpr float TAU = 0.01f;     // ~11-sigma screen-gap guard (R13/R14 clean)

// monotone fp32 -> u32 map (min preserved) — R3-proven
__device__ __forceinline__ uint32_t fmap(float v) {
    uint32_t u = __float_as_uint(v);
    return (u & 0x80000000u) ? ~u : (u | 0x80000000u);
}
__device__ __forceinline__ float funmap(uint32_t m) {
    uint32_t u = (m & 0x80000000u) ? (m ^ 0x80000000u) : ~m;
    return __uint_as_float(u);
}
__device__ __forceinline__ void top2_merge(u64& b, u64& s, u64 ob, u64 os) {
    if (ob < b) { s = (b < os) ? b : os; b = ob; }
    else        { s = (ob < s) ? ob : s; }
}
__device__ __forceinline__ u64 shfl_xor_u64(u64 v, int m) {
    uint32_t lo = (uint32_t)v, hi = (uint32_t)(v >> 32);
    lo = (uint32_t)__shfl_xor((int)lo, m, 64);
    hi = (uint32_t)__shfl_xor((int)hi, m, 64);
    return ((u64)hi << 32) | lo;
}
__device__ __forceinline__ double shfl_xor_f64(double v, int m) {
    int lo = __double2loint(v), hi = __double2hiint(v);
    lo = __shfl_xor(lo, m, 64);
    hi = __shfl_xor(hi, m, 64);
    return __hiloint2double(hi, lo);
}
// 8 fp32 -> 8 fp16 (RNE) fragment
__device__ __forceinline__ void cvt8h(float4 a, float4 b, half8& H) {
    H[0] = (_Float16)a.x; H[1] = (_Float16)a.y;
    H[2] = (_Float16)a.z; H[3] = (_Float16)a.w;
    H[4] = (_Float16)b.x; H[5] = (_Float16)b.y;
    H[6] = (_Float16)b.z; H[7] = (_Float16)b.w;
}

// ---- prep: e_sq (f64/f32), ET[k][d] gather table, Bh fragment-linear fp16
//      table of -2E. grid 256 x 256. ----
__global__ __launch_bounds__(256) void vq_prep(const float* __restrict__ E,
                                               double* __restrict__ e_sq64,
                                               float* __restrict__ e_sq32,
                                               float* __restrict__ ET,
                                               _Float16* __restrict__ Bh) {
    int tid = blockIdx.x * 256 + threadIdx.x;        // 0..65535
    if (tid < K) {
        int k = tid;
        double s = 0.0;
        for (int d = 0; d < D; ++d) {
            float v = E[d * K + k];
            s = fma((double)v, (double)v, s);
            ET[k * D + d] = v;
        }
        e_sq64[k] = s;
        e_sq32[k] = (float)s;
    }
    // table entry: frag f = t*2+c (t=tile 0..63, c=k-chunk 0..1), lane l, slot j
    //   value = fp16(-2*E[d][code]), d = 32c + 8*(l>>4) + j, code = 16t + (l&15)
    //   half index = t*1024 + c*512 + l*8 + j  (tile t = 2KB contiguous)
    {
        int j = tid & 7;
        int l = (tid >> 3) & 63;
        int f = tid >> 9;            // 0..127
        int c = f & 1;
        int t = f >> 1;
        int d = 32 * c + 8 * (l >> 4) + j;
        int code = 16 * t + (l & 15);
        Bh[tid] = (_Float16)(-2.0f * E[d * K + code]);
    }
}

// ---- screen + per-wave refine: block = 512 rows (8 waves x 64), 1 block/CU ----
__global__ __launch_bounds__(512, 2) void vq_screen(
    const float* __restrict__ x, const _Float16* __restrict__ Bh,
    const float* __restrict__ e_sq32, const double* __restrict__ e_sq64,
    const float* __restrict__ ET, float* __restrict__ out) {
    __shared__ _Float16 Bt[K * D];             // 128 KB: the whole B table
    __shared__ float esq[K];                   // 4 KB
    __shared__ int bk[512];                    // 2 KB
    __shared__ double xsw[8][D];               // 4 KB (per-wave refine staging)
    __shared__ int flag_list[512];             // 2 KB
    __shared__ int flag_n;

    const int t0 = threadIdx.x;
    const int base = blockIdx.x * 512;

    if (t0 == 0) flag_n = 0;

    // stage e_sq (512 threads x 2)
    esq[t0] = e_sq32[t0];
    esq[512 + t0] = e_sq32[512 + t0];

    const int wid = t0 >> 6, l = t0 & 63;      // wid in 0..7
    const int col = l & 15, quad = l >> 4;

    // stage the full 128 KB table: 16 iterations x (8 waves x 64 lanes x 16 B).
    // dst base wave-uniform (i*4096 + wid*512 halfs); lane data lands at +l*16B.
    // src per-lane mirrors the same linear offset (m104/m108).
    #pragma unroll
    for (int i = 0; i < 16; ++i) {
        const _Float16* src = Bh + i * 4096 + wid * 512 + l * 8;
        __builtin_amdgcn_global_load_lds(
            (const __attribute__((address_space(1))) void*)src,
            (__attribute__((address_space(3))) void*)&Bt[i * 4096 + wid * 512],
            16, 0, 0);
    }

    // A fragments for 4 rowsets (wave owns rows [wid*64, wid*64+64)),
    // loaded DIRECTLY from global in fragment order (verified layout:
    // m = lane&15, k = quad*8 + j, k-chunks at 0 and 32), fp16 in registers.
    half8 A0[4], A1[4];
    #pragma unroll
    for (int s = 0; s < 4; ++s) {
        const float* xr = x + (size_t)(base + wid * 64 + s * 16 + col) * D + quad * 8;
        float4 p0 = *(const float4*)(xr);
        float4 p1 = *(const float4*)(xr + 4);
        float4 p2 = *(const float4*)(xr + 32);
        float4 p3 = *(const float4*)(xr + 36);
        cvt8h(p0, p1, A0[s]);
        cvt8h(p2, p3, A1[s]);
    }

    float best[4][4], sec[4][4];
    int bidx[4][4];
    #pragma unroll
    for (int s = 0; s < 4; ++s)
        #pragma unroll
        for (int r = 0; r < 4; ++r) {
            best[s][r] = 3.4e38f; sec[s][r] = 3.4e38f; bidx[s][r] = 0;
        }

    __syncthreads();   // drains staging (vmcnt0) + esq; table ready for all

    // prologue: tile 0 frags from LDS
    half8 b0c = *(const half8*)&Bt[l * 8];
    half8 b1c = *(const half8*)&Bt[512 + l * 8];
    float esv_c = esq[col];

    #pragma unroll 2
    for (int t = 0; t < 64; ++t) {
        // depth-1 LDS prefetch of tile t+1 (t=63 wraps to 0 — unused values)
        int tn = (t + 1) & 63;
        half8 b0n = *(const half8*)&Bt[tn * 1024 + l * 8];
        half8 b1n = *(const half8*)&Bt[tn * 1024 + 512 + l * 8];
        float esv_n = esq[tn * 16 + col];
        // pin issue order: reads above stay above the MFMA cluster (R9 pattern)
        __builtin_amdgcn_sched_barrier(0);

        int tc = t * 16;
        // 4 independent depth-2 MFMA chains (one per rowset) -> matrix-pipe ILP
        #pragma unroll
        for (int s = 0; s < 4; ++s) {
            f32x4 C = {esv_c, esv_c, esv_c, esv_c};
            C = __builtin_amdgcn_mfma_f32_16x16x32_f16(A0[s], b0c, C, 0, 0, 0);
            C = __builtin_amdgcn_mfma_f32_16x16x32_f16(A1[s], b1c, C, 0, 0, 0);
            #pragma unroll
            for (int r = 0; r < 4; ++r) {
                float v = C[r];
                bool lt = v < best[s][r];
                float mx = fmaxf(v, best[s][r]);
                best[s][r] = fminf(v, best[s][r]);
                sec[s][r]  = fminf(sec[s][r], mx);
                bidx[s][r] = lt ? tc : bidx[s][r];
            }
        }
        b0c = b0n; b1c = b1n; esv_c = esv_n;
    }

    // per-register reduce across the 16 col-lanes (masks 1..8 preserve quad)
    #pragma unroll
    for (int s = 0; s < 4; ++s)
        #pragma unroll
        for (int r = 0; r < 4; ++r) {
            u64 b = ((u64)fmap(best[s][r]) << 32) | (uint32_t)(bidx[s][r] + col);
            u64 sv = ((u64)fmap(sec[s][r]) << 32) | 0xFFFFFFFFu;
            #pragma unroll
            for (int m = 8; m >= 1; m >>= 1) {
                u64 ob = shfl_xor_u64(b, m);
                u64 os = shfl_xor_u64(sv, m);
                top2_merge(b, sv, ob, os);
            }
            if (col == 0) {
                int rowL = wid * 64 + s * 16 + quad * 4 + r;  // verified C row map
                bk[rowL] = (int)(uint32_t)(b & 0xFFFFFFFFu);
                float vb = funmap((uint32_t)(b >> 32));
                float vs = funmap((uint32_t)(sv >> 32));
                if (vs - vb < TAU) {
                    int idx = atomicAdd(&flag_n, 1);
                    flag_list[idx] = rowL;
                }
            }
        }
    __syncthreads();

    // per-WAVE-parallel exact fp64 refine (R14-proven): rows striped across
    // 8 waves, zero barriers inside. Lane l owns codes l*16..l*16+15
    // (ascending within lane); butterfly keeps lowest k on exact ties ->
    // identical semantics to the proven refine (ET[k*D+d]==E[d*K+k] exactly,
    // fp64 fma ascending d, e_sq64 C-term).
    {
        int nf = flag_n;                         // uniform across block
        for (int f = wid; f < nf; f += 8) {
            int rowR = flag_list[f];
            xsw[wid][l] = (double)x[(size_t)(base + rowR) * D + l];
            asm volatile("s_waitcnt lgkmcnt(0)" ::: "memory");
            __builtin_amdgcn_sched_barrier(0);   // rule #18: fence the ds reads
            double bestd = 1.0e300; int bestk = 0;
            #pragma unroll 4
            for (int j = 0; j < 16; ++j) {
                int k = l * 16 + j;
                const float* ep = ET + (size_t)k * D;
                double a = 0.0;
                #pragma unroll 8
                for (int d = 0; d < D; ++d)
                    a = fma(xsw[wid][d], (double)ep[d], a);
                double v = fma(-2.0, a, e_sq64[k]);
                if (v < bestd) { bestd = v; bestk = k; }
            }
            #pragma unroll
            for (int m = 32; m >= 1; m >>= 1) {
                double ov = shfl_xor_f64(bestd, m);
                int    ok = __shfl_xor(bestk, m, 64);
                if (ov < bestd || (ov == bestd && ok < bestk)) { bestd = ov; bestk = ok; }
            }
            if (l == 0) bk[rowR] = bestk;
        }
    }
    __syncthreads();

    // gather: thread t0 copies its whole row (256 B) from ET
    {
        const float4* ep = (const float4*)(ET + (size_t)bk[t0] * D);
        float4* op = (float4*)(out + (size_t)(base + t0) * D);
        #pragma unroll
        for (int q = 0; q < 16; ++q) op[q] = ep[q];
    }
}

extern "C" void kernel_launch(void* const* d_in, const int* in_sizes, int n_in,
                              void* d_out, int out_size, void* d_ws, size_t ws_size,
                              hipStream_t stream) {
    const float* x = (const float*)d_in[0];
    const float* E = (const float*)d_in[1];
    float* out = (float*)d_out;
    int N = in_sizes[0] / D;   // 131072

    // ws: e_sq64 8K | e_sq32 4K | ET 256K | Bh 128K (fp16)
    char* w = (char*)d_ws;
    double*    e_sq64 = (double*)w;     w += K * sizeof(double);
    float*     e_sq32 = (float*)w;      w += K * sizeof(float);
    float*     ET     = (float*)w;      w += (size_t)K * D * sizeof(float);
    _Float16*  Bh     = (_Float16*)w;   w += (size_t)K * D * sizeof(_Float16);

    vq_prep<<<256, 256, 0, stream>>>(E, e_sq64, e_sq32, ET, Bh);
    vq_screen<<<N / 512, 512, 0, stream>>>(x, Bh, e_sq32, e_sq64, ET, out);
}

// Round 11
// 272.841 us; speedup vs baseline: 1.0971x; 1.0971x over previous
//
#include <hip/hip_runtime.h>
#include <hip/hip_bf16.h>
#include <stdint.h>

// VQ: x [N=131072, D=64] fp32, E [D=64, K=1024] fp32.
// R16: minimal-VALU body x maximal TLP. Cross-round law (R6-R15): VALU-busy
// TIME is ~40us in every structure; wall = 40us / VALUBusy-frac. Fixes:
// (1) 1 rowset/wave -> per-wave live set ~45 VGPR (R14/15's 4-rowset
//     accumulator arrays reported VGPR 84-88 < live-set estimate => spills/
//     accvgpr churn were the hidden VALU inflation);
// (2) grid 2048, 256-thr blocks, launch_bounds(256,8) -> 8 waves/SIMD FULL
//     residency in one round -> busy-frac up;
// (3) NO prefetch, NO sched_barrier: 8 waves x ~80cyc body >> 300cyc L2
//     latency; compiler pipelines freely.
// fp16 1-term screen + TAU=0.01 + per-wave fp64 refine: validated R13-R15
// (absmax=0). Verified facts: A[m=lane&15][k=(lane>>4)*8+j] (m89/m91/m120),
// C/D col=lane&15 row=(lane>>4)*4+reg (m89/m91, dtype-indep m121-m128).

typedef unsigned long long u64;
typedef _Float16 half8 __attribute__((ext_vector_type(8)));
typedef float f32x4 __attribute__((ext_vector_type(4)));

constexpr int D = 64;
constexpr int K = 1024;
constexpr float TAU = 0.01f;     // ~11-sigma screen-gap guard (R13-R15 clean)

// monotone fp32 -> u32 map (min preserved) — R3-proven
__device__ __forceinline__ uint32_t fmap(float v) {
    uint32_t u = __float_as_uint(v);
    return (u & 0x80000000u) ? ~u : (u | 0x80000000u);
}
__device__ __forceinline__ float funmap(uint32_t m) {
    uint32_t u = (m & 0x80000000u) ? (m ^ 0x80000000u) : ~m;
    return __uint_as_float(u);
}
__device__ __forceinline__ void top2_merge(u64& b, u64& s, u64 ob, u64 os) {
    if (ob < b) { s = (b < os) ? b : os; b = ob; }
    else        { s = (ob < s) ? ob : s; }
}
__device__ __forceinline__ u64 shfl_xor_u64(u64 v, int m) {
    uint32_t lo = (uint32_t)v, hi = (uint32_t)(v >> 32);
    lo = (uint32_t)__shfl_xor((int)lo, m, 64);
    hi = (uint32_t)__shfl_xor((int)hi, m, 64);
    return ((u64)hi << 32) | lo;
}
__device__ __forceinline__ double shfl_xor_f64(double v, int m) {
    int lo = __double2loint(v), hi = __double2hiint(v);
    lo = __shfl_xor(lo, m, 64);
    hi = __shfl_xor(hi, m, 64);
    return __hiloint2double(hi, lo);
}
// 8 fp32 -> 8 fp16 (RNE) fragment
__device__ __forceinline__ void cvt8h(float4 a, float4 b, half8& H) {
    H[0] = (_Float16)a.x; H[1] = (_Float16)a.y;
    H[2] = (_Float16)a.z; H[3] = (_Float16)a.w;
    H[4] = (_Float16)b.x; H[5] = (_Float16)b.y;
    H[6] = (_Float16)b.z; H[7] = (_Float16)b.w;
}

// ---- prep: e_sq (f64/f32), ET[k][d] gather table, Bh fragment-linear fp16
//      table of -2E. grid 256 x 256. ----
__global__ __launch_bounds__(256) void vq_prep(const float* __restrict__ E,
                                               double* __restrict__ e_sq64,
                                               float* __restrict__ e_sq32,
                                               float* __restrict__ ET,
                                               _Float16* __restrict__ Bh) {
    int tid = blockIdx.x * 256 + threadIdx.x;        // 0..65535
    if (tid < K) {
        int k = tid;
        double s = 0.0;
        for (int d = 0; d < D; ++d) {
            float v = E[d * K + k];
            s = fma((double)v, (double)v, s);
            ET[k * D + d] = v;
        }
        e_sq64[k] = s;
        e_sq32[k] = (float)s;
    }
    // table entry: frag f = t*2+c (t=tile 0..63, c=k-chunk 0..1), lane l, slot j
    //   value = fp16(-2*E[d][code]), d = 32c + 8*(l>>4) + j, code = 16t + (l&15)
    //   half index = t*1024 + c*512 + l*8 + j  (tile t = 2KB contiguous)
    {
        int j = tid & 7;
        int l = (tid >> 3) & 63;
        int f = tid >> 9;            // 0..127
        int c = f & 1;
        int t = f >> 1;
        int d = 32 * c + 8 * (l >> 4) + j;
        int code = 16 * t + (l & 15);
        Bh[tid] = (_Float16)(-2.0f * E[d * K + code]);
    }
}

// ---- screen + per-wave refine: block = 64 rows (4 waves x 16), 8 blk/CU ----
__global__ __launch_bounds__(256, 8) void vq_screen(
    const float* __restrict__ x, const half8* __restrict__ Bh,
    const float* __restrict__ e_sq32, const double* __restrict__ e_sq64,
    const float* __restrict__ ET, float* __restrict__ out) {
    __shared__ float esq[K];                   // 4 KB
    __shared__ int bk[64];                     // 0.25 KB
    __shared__ double xsw[4][D];               // 2 KB (per-wave refine staging)
    __shared__ int flag_list[64];              // 0.25 KB
    __shared__ int flag_n;

    const int t0 = threadIdx.x;
    const int base = blockIdx.x * 64;

    if (t0 == 0) flag_n = 0;

    // stage e_sq
    #pragma unroll
    for (int i = 0; i < 4; ++i) esq[i * 256 + t0] = e_sq32[i * 256 + t0];

    const int wid = t0 >> 6, l = t0 & 63;
    const int col = l & 15, quad = l >> 4;

    // A fragments, 1 rowset/wave (wave owns rows [wid*16, wid*16+16)),
    // loaded directly from global in fragment order (verified layout:
    // m = lane&15, k = quad*8 + j, k-chunks at 0 and 32), fp16 in registers.
    half8 A0, A1;
    {
        const float* xr = x + (size_t)(base + wid * 16 + col) * D + quad * 8;
        float4 p0 = *(const float4*)(xr);
        float4 p1 = *(const float4*)(xr + 4);
        float4 p2 = *(const float4*)(xr + 32);
        float4 p3 = *(const float4*)(xr + 36);
        cvt8h(p0, p1, A0);
        cvt8h(p2, p3, A1);
    }

    float best[4], sec[4];
    int bidx[4];
    #pragma unroll
    for (int r = 0; r < 4; ++r) { best[r] = 3.4e38f; sec[r] = 3.4e38f; bidx[r] = 0; }

    __syncthreads();   // esq + flag_n ready

    // minimal body: 2 loads + 1 ds_read + 2 MFMA + 5-op/value min-update.
    // No prefetch / no pin: 8 waves/SIMD provide the latency hiding (TLP),
    // and the compiler is free to batch loads across unrolled iterations.
    #pragma unroll 4
    for (int t = 0; t < 64; ++t) {
        half8 b0 = Bh[t * 128 + l];
        half8 b1 = Bh[t * 128 + 64 + l];
        float esv = esq[t * 16 + col];

        f32x4 C = {esv, esv, esv, esv};
        C = __builtin_amdgcn_mfma_f32_16x16x32_f16(A0, b0, C, 0, 0, 0);
        C = __builtin_amdgcn_mfma_f32_16x16x32_f16(A1, b1, C, 0, 0, 0);

        int tc = t * 16;
        #pragma unroll
        for (int r = 0; r < 4; ++r) {
            float v = C[r];
            bool lt = v < best[r];
            float mx = fmaxf(v, best[r]);
            best[r] = fminf(v, best[r]);
            sec[r]  = fminf(sec[r], mx);
            bidx[r] = lt ? tc : bidx[r];
        }
    }

    // per-register reduce across the 16 col-lanes (masks 1..8 preserve quad)
    #pragma unroll
    for (int r = 0; r < 4; ++r) {
        u64 b = ((u64)fmap(best[r]) << 32) | (uint32_t)(bidx[r] + col);
        u64 s = ((u64)fmap(sec[r]) << 32) | 0xFFFFFFFFu;
        #pragma unroll
        for (int m = 8; m >= 1; m >>= 1) {
            u64 ob = shfl_xor_u64(b, m);
            u64 os = shfl_xor_u64(s, m);
            top2_merge(b, s, ob, os);
        }
        if (col == 0) {
            int rowL = wid * 16 + quad * 4 + r;        // verified C row map
            bk[rowL] = (int)(uint32_t)(b & 0xFFFFFFFFu);
            float vb = funmap((uint32_t)(b >> 32));
            float vs = funmap((uint32_t)(s >> 32));
            if (vs - vb < TAU) {
                int idx = atomicAdd(&flag_n, 1);
                flag_list[idx] = rowL;
            }
        }
    }
    __syncthreads();

    // per-WAVE-parallel exact fp64 refine (R14/R15-proven): rows striped
    // across 4 waves, zero barriers inside. Lane l owns codes l*16..l*16+15
    // (ascending within lane); butterfly keeps lowest k on exact ties ->
    // identical semantics to the proven refine (ET[k*D+d]==E[d*K+k] exactly,
    // fp64 fma ascending d, e_sq64 C-term).
    {
        int nf = flag_n;                         // uniform across block
        for (int f = wid; f < nf; f += 4) {
            int rowR = flag_list[f];
            xsw[wid][l] = (double)x[(size_t)(base + rowR) * D + l];
            asm volatile("s_waitcnt lgkmcnt(0)" ::: "memory");
            __builtin_amdgcn_sched_barrier(0);   // rule #18: fence the ds reads
            double bestd = 1.0e300; int bestk = 0;
            #pragma unroll 4
            for (int j = 0; j < 16; ++j) {
                int k = l * 16 + j;
                const float* ep = ET + (size_t)k * D;
                double a = 0.0;
                #pragma unroll 8
                for (int d = 0; d < D; ++d)
                    a = fma(xsw[wid][d], (double)ep[d], a);
                double v = fma(-2.0, a, e_sq64[k]);
                if (v < bestd) { bestd = v; bestk = k; }
            }
            #pragma unroll
            for (int m = 32; m >= 1; m >>= 1) {
                double ov = shfl_xor_f64(bestd, m);
                int    ok = __shfl_xor(bestk, m, 64);
                if (ov < bestd || (ov == bestd && ok < bestk)) { bestd = ov; bestk = ok; }
            }
            if (l == 0) bk[rowR] = bestk;
        }
    }
    __syncthreads();

    // gather: 4 threads/row, each copies 64 B from ET
    {
        int row = t0 >> 2, seg = t0 & 3;
        const float4* ep = (const float4*)(ET + (size_t)bk[row] * D + seg * 16);
        float4* op = (float4*)(out + (size_t)(base + row) * D + seg * 16);
        op[0] = ep[0]; op[1] = ep[1]; op[2] = ep[2]; op[3] = ep[3];
    }
}

extern "C" void kernel_launch(void* const* d_in, const int* in_sizes, int n_in,
                              void* d_out, int out_size, void* d_ws, size_t ws_size,
                              hipStream_t stream) {
    const float* x = (const float*)d_in[0];
    const float* E = (const float*)d_in[1];
    float* out = (float*)d_out;
    int N = in_sizes[0] / D;   // 131072

    // ws: e_sq64 8K | e_sq32 4K | ET 256K | Bh 128K (fp16)
    char* w = (char*)d_ws;
    double*    e_sq64 = (double*)w;     w += K * sizeof(double);
    float*     e_sq32 = (float*)w;      w += K * sizeof(float);
    float*     ET     = (float*)w;      w += (size_t)K * D * sizeof(float);
    _Float16*  Bh     = (_Float16*)w;   w += (size_t)K * D * sizeof(_Float16);

    vq_prep<<<256, 256, 0, stream>>>(E, e_sq64, e_sq32, ET, Bh);
    vq_screen<<<N / 64, 256, 0, stream>>>(x, (const half8*)Bh,
                                          e_sq32, e_sq64, ET, out);
}